// Round 4
// baseline (410.960 us; speedup 1.0000x reference)
//
#include <hip/hip_runtime.h>

// Problem constants (fixed by setup_inputs)
#define NB 16
#define NE 8
#define NH 512
#define NW 1024
#define HW (NH * NW)            // 524288 pixels per image
#define TPB 256
#define CH2 128                 // chunks per (b,e) channel slice
#define PXC (HW / CH2)          // 4096 pixels per block
#define GRP (PXC / (TPB * 4))   // 4 groups of 4 px per thread
#define ACC2 68                 // per-b: cnt[4], ssqe[4][8], sums[4][8]

// Native clang vector type for clean 16B loads.
typedef float floatx4 __attribute__((ext_vector_type(4)));

// Stage 1, CHANNEL-SLICE blocks: each block owns one (b, e, chunk) — a
// perfectly contiguous 16 KiB pred run plus the 16 KiB label chunk.
//
// Rationale vs the two prior structures:
//  - round-0 (394.5us): 9 interleaved 2MiB-strided streams, ~130+ VGPR state
//    -> ~3 blocks/CU resident, long tail; partial ~66us (4.6 TB/s).
//  - round-2/3 channel-major (409/405us): serial label-phase head + 2-deep
//    rotation stalls the pipe. REGRESSED -> stream-interleave was not the issue.
//  - this: all 8 loads/thread issue up-front (same in-flight depth as round-0),
//    only 12 accumulator floats -> ~64 VGPR -> ~2x occupancy, short tail.
// Labels are read by the 8 channel-blocks of a chunk; e is the FASTEST grid
// dim so those 8 dispatch back-to-back and 7/8 label reads hit the shared
// 256 MiB L3 (16 KiB window, us-scale reuse). HBM label traffic stays ~32 MiB.
// ssq is accumulated per-(l,e) into acc and folded over e in finalize, keeping
// atomic contention at 128 contributors/address (same as sums).
__global__ __launch_bounds__(TPB) void cluster_partial(
    const float* __restrict__ pred, const int* __restrict__ lab,
    float* __restrict__ acc)
{
    const int bid   = blockIdx.x;
    const int e     = bid & (NE - 1);
    const int rest  = bid >> 3;
    const int chunk = rest & (CH2 - 1);
    const int b     = rest >> 7;
    const int t     = threadIdx.x;

    const float* predb = pred + ((long)b * NE + e) * HW + chunk * PXC;
    const int*   labb  = lab  + (long)b * HW           + chunk * PXC;
    const int    toff  = t << 2;

    // issue all 8 loads up-front; compute waits per-use on vmcnt
    int4    L[GRP];
    floatx4 V[GRP];
#pragma unroll
    for (int g = 0; g < GRP; ++g)
        L[g] = *reinterpret_cast<const int4*>(labb + g * (TPB * 4) + toff);
#pragma unroll
    for (int g = 0; g < GRP; ++g)
        V[g] = *reinterpret_cast<const floatx4*>(predb + g * (TPB * 4) + toff);

    float cn[4] = {0.f, 0.f, 0.f, 0.f};
    float sq[4] = {0.f, 0.f, 0.f, 0.f};
    float se[4] = {0.f, 0.f, 0.f, 0.f};

#pragma unroll
    for (int g = 0; g < GRP; ++g) {
        const int lbs[4] = {L[g].x, L[g].y, L[g].z, L[g].w};
#pragma unroll
        for (int p = 0; p < 4; ++p) {
            const float x  = V[g][p];
            const float x2 = x * x;
#pragma unroll
            for (int l = 0; l < 4; ++l) {
                const float m = (lbs[p] == l + 1) ? 1.0f : 0.0f;
                se[l] = fmaf(m, x,  se[l]);
                sq[l] = fmaf(m, x2, sq[l]);
            }
        }
        if (e == 0) {   // block-uniform branch: only channel-0 blocks count px
#pragma unroll
            for (int p = 0; p < 4; ++p)
#pragma unroll
                for (int l = 0; l < 4; ++l)
                    cn[l] += (lbs[p] == l + 1) ? 1.0f : 0.0f;
        }
    }

    // 12 per-thread partials; wave(64) shuffle reduction, then 4-wave LDS sum.
    float vals[12];
#pragma unroll
    for (int l = 0; l < 4; ++l) {
        vals[l]     = cn[l];
        vals[4 + l] = sq[l];
        vals[8 + l] = se[l];
    }
#pragma unroll
    for (int i = 0; i < 12; ++i) {
        float vv = vals[i];
        vv += __shfl_down(vv, 32);
        vv += __shfl_down(vv, 16);
        vv += __shfl_down(vv, 8);
        vv += __shfl_down(vv, 4);
        vv += __shfl_down(vv, 2);
        vv += __shfl_down(vv, 1);
        vals[i] = vv;
    }

    __shared__ float red[TPB / 64][12];
    const int wave = t >> 6;
    const int lane = t & 63;
    if (lane == 0) {
#pragma unroll
        for (int i = 0; i < 12; ++i) red[wave][i] = vals[i];
    }
    __syncthreads();
    if (t < 12) {
        const float s = red[0][t] + red[1][t] + red[2][t] + red[3][t];
        if (t < 4) {
            if (e == 0) atomicAdd(&acc[b * ACC2 + t], s);
        } else if (t < 8) {
            atomicAdd(&acc[b * ACC2 + 4  + (t - 4) * NE + e], s);
        } else {
            atomicAdd(&acc[b * ACC2 + 36 + (t - 8) * NE + e], s);
        }
    }
}

// Stage 2: tiny finalize — one thread per batch image, wave-reduce, write scalar.
__global__ __launch_bounds__(64) void cluster_finalize(
    const float* __restrict__ acc, float* __restrict__ out)
{
    const int t = threadIdx.x;
    float Lb = 0.f;
    if (t < NB) {
        const float* a = acc + t * ACC2;
        float mu[4][NE];   // cluster means for labels 0..3 (mu_d); mu[0] == 0
#pragma unroll
        for (int e = 0; e < NE; ++e) mu[0][e] = 0.f;

        float Lvar = 0.f;
#pragma unroll
        for (int l = 1; l <= 4; ++l) {
            const float c = a[l - 1];
            float ssq = 0.f;
#pragma unroll
            for (int e = 0; e < NE; ++e) ssq += a[4 + (l - 1) * NE + e];
            float mloc[NE];
            float musq = 0.f;
#pragma unroll
            for (int e = 0; e < NE; ++e) {
                mloc[e] = a[36 + (l - 1) * NE + e] / c;
                musq = fmaf(mloc[e], mloc[e], musq);
            }
            const float frob = ssq - c * musq;
            const float n = (frob > 0.f) ? sqrtf(frob) : 0.f;
            const float dv = n - 0.5f;               // DELTA_V = 0.5
            Lvar += (n > 0.5f) ? dv * dv : 0.f;
            if (l < 4) {
#pragma unroll
                for (int e = 0; e < NE; ++e) mu[l][e] = mloc[e];
            }
        }
        Lvar *= 0.25f;  // / C

        float Ldist = 0.f;
#pragma unroll
        for (int i = 0; i < 4; ++i)
#pragma unroll
            for (int j = i + 1; j < 4; ++j) {
                float dsq = 0.f;
#pragma unroll
                for (int e = 0; e < NE; ++e) {
                    const float d = mu[i][e] - mu[j][e];
                    dsq = fmaf(d, d, dsq);
                }
                float h;
                if (dsq > 0.f) {
                    const float d = sqrtf(dsq);
                    float r = 3.0f - d;              // DELTA_D = 3.0
                    r = (r > 0.f) ? r : 0.f;
                    h = r * r;
                } else {
                    h = 9.0f;                        // DELTA_D^2
                }
                Ldist += 2.0f * h;                   // both (i,j) and (j,i)
            }

        Lb = (Lvar + Ldist) * (1.0f / NB);           // mean over B of both terms
    }
    Lb += __shfl_down(Lb, 32);
    Lb += __shfl_down(Lb, 16);
    Lb += __shfl_down(Lb, 8);
    Lb += __shfl_down(Lb, 4);
    Lb += __shfl_down(Lb, 2);
    Lb += __shfl_down(Lb, 1);
    if (t == 0) out[0] = Lb;
}

extern "C" void kernel_launch(void* const* d_in, const int* in_sizes, int n_in,
                              void* d_out, int out_size, void* d_ws, size_t ws_size,
                              hipStream_t stream) {
    const float* pred = (const float*)d_in[0];
    // d_in[1] = binary_label: unused — it is exactly (instance_label > 0).
    const int* lab = (const int*)d_in[2];
    float* out = (float*)d_out;
    float* acc = (float*)d_ws;   // NB*68 floats = 4352 B, ws is poisoned -> zero it

    (void)hipMemsetAsync(acc, 0, NB * ACC2 * sizeof(float), stream);
    cluster_partial<<<NB * CH2 * NE, TPB, 0, stream>>>(pred, lab, acc);
    cluster_finalize<<<1, 64, 0, stream>>>(acc, out);
}

// Round 5
// 393.559 us; speedup vs baseline: 1.0442x; 1.0442x over previous
//
#include <hip/hip_runtime.h>

// Problem constants (fixed by setup_inputs)
#define NB 16
#define NE 8
#define NH 512
#define NW 1024
#define HW (NH * NW)            // 524288 pixels per image
#define CHUNKS 128              // blocks per image (2048 total, 8 blocks/CU)
#define TPB 256
#define PIX_PER_CHUNK (HW / CHUNKS)         // 4096
#define GROUPS (PIX_PER_CHUNK / (TPB * 4))  // 4 groups of 4 pixels per thread
#define ACC_STRIDE 40           // per-b: cnt[4], sumsq[4], sums[4][8]

// REVERT to the round-0 structure. Experiment ledger on this problem:
//   r0 9-stream interleaved pipelined:            394.5 us  <- best
//   r2 channel-major sweep + nontemporal loads:   409.5 us
//   r3 channel-major sweep, cached loads:         404.7 us
//   r4 channel-slice blocks (1 (b,e,chunk)/block):411.0 us
// All "cleaner-stream" restructures LOST ~10-16 us: the 9-stream interleave
// with deep per-wave pipelining is the best schedule found for this access
// shape. 394.5 = 2x~161us harness poison fills (84% HBM peak, untouchable)
// + ~66us partial (288 MiB read @ ~4.6 TB/s) + ~6us fixed overhead.

// Stage 1: per-block partial statistics, atomically accumulated into acc[b][40].
// Label 0 contributes nothing (binary_label == (label>0) zeroes pred_roi), so we
// only track labels 1..4. binary_label input is therefore never read.
// g-loop is software-pipelined: group g+1's 9 loads (1 int4 + 8 float4) issue
// before group g's FMA work, so waves don't stall on vmcnt every iteration.
__global__ __launch_bounds__(TPB) void cluster_partial(
    const float* __restrict__ pred, const int* __restrict__ lab,
    float* __restrict__ acc)
{
    const int b     = blockIdx.x / CHUNKS;
    const int chunk = blockIdx.x % CHUNKS;
    const int t     = threadIdx.x;

    const float* predb = pred + (long)b * NE * HW;
    const int*   labb  = lab  + (long)b * HW;
    const int base0 = chunk * PIX_PER_CHUNK + (t << 2);

    float sums[4][NE];
    float ssq_acc[4] = {0.f, 0.f, 0.f, 0.f};
    float cnt[4]     = {0.f, 0.f, 0.f, 0.f};
#pragma unroll
    for (int l = 0; l < 4; ++l)
#pragma unroll
        for (int e = 0; e < NE; ++e) sums[l][e] = 0.f;

    // prime the pipeline: group 0 loads
    int4   l4 = *reinterpret_cast<const int4*>(labb + base0);
    float4 v[NE];
#pragma unroll
    for (int e = 0; e < NE; ++e)
        v[e] = *reinterpret_cast<const float4*>(predb + (long)e * HW + base0);

#pragma unroll
    for (int g = 0; g < GROUPS; ++g) {
        // prefetch group g+1 while computing group g
        int4   l4n = l4;
        float4 vn[NE];
#pragma unroll
        for (int e = 0; e < NE; ++e) vn[e] = v[e];
        if (g + 1 < GROUPS) {
            const int off = base0 + (g + 1) * (TPB * 4);
            l4n = *reinterpret_cast<const int4*>(labb + off);
#pragma unroll
            for (int e = 0; e < NE; ++e)
                vn[e] = *reinterpret_cast<const float4*>(predb + (long)e * HW + off);
        }

        const int labs[4] = {l4.x, l4.y, l4.z, l4.w};

        // one-hot masks for labels 1..4 (label 0 -> all zero)
        float m[4][4];
#pragma unroll
        for (int p = 0; p < 4; ++p)
#pragma unroll
            for (int l = 0; l < 4; ++l)
                m[p][l] = (labs[p] == l + 1) ? 1.0f : 0.0f;

        float ssq[4] = {0.f, 0.f, 0.f, 0.f};
#pragma unroll
        for (int e = 0; e < NE; ++e) {
            const float vv[4] = {v[e].x, v[e].y, v[e].z, v[e].w};
#pragma unroll
            for (int p = 0; p < 4; ++p) {
                ssq[p] = fmaf(vv[p], vv[p], ssq[p]);
#pragma unroll
                for (int l = 0; l < 4; ++l)
                    sums[l][e] = fmaf(m[p][l], vv[p], sums[l][e]);
            }
        }
#pragma unroll
        for (int p = 0; p < 4; ++p)
#pragma unroll
            for (int l = 0; l < 4; ++l) {
                ssq_acc[l] = fmaf(m[p][l], ssq[p], ssq_acc[l]);
                cnt[l] += m[p][l];
            }

        l4 = l4n;
#pragma unroll
        for (int e = 0; e < NE; ++e) v[e] = vn[e];
    }

    // Pack 40 per-thread partials; wave(64)-level shuffle reduction.
    float vals[ACC_STRIDE];
#pragma unroll
    for (int l = 0; l < 4; ++l) {
        vals[l]     = cnt[l];
        vals[4 + l] = ssq_acc[l];
#pragma unroll
        for (int e = 0; e < NE; ++e) vals[8 + l * NE + e] = sums[l][e];
    }
#pragma unroll
    for (int i = 0; i < ACC_STRIDE; ++i) {
        float vv = vals[i];
        vv += __shfl_down(vv, 32);
        vv += __shfl_down(vv, 16);
        vv += __shfl_down(vv, 8);
        vv += __shfl_down(vv, 4);
        vv += __shfl_down(vv, 2);
        vv += __shfl_down(vv, 1);
        vals[i] = vv;
    }

    __shared__ float red[TPB / 64][ACC_STRIDE];
    const int wave = t >> 6;
    const int lane = t & 63;
    if (lane == 0) {
#pragma unroll
        for (int i = 0; i < ACC_STRIDE; ++i) red[wave][i] = vals[i];
    }
    __syncthreads();
    if (t < ACC_STRIDE) {
        float s = red[0][t] + red[1][t] + red[2][t] + red[3][t];
        atomicAdd(&acc[b * ACC_STRIDE + t], s);
    }
}

// Stage 2: tiny finalize — one thread per batch image, wave-reduce, write scalar.
__global__ __launch_bounds__(64) void cluster_finalize(
    const float* __restrict__ acc, float* __restrict__ out)
{
    const int t = threadIdx.x;
    float Lb = 0.f;
    if (t < NB) {
        const float* a = acc + t * ACC_STRIDE;
        float mu[4][NE];   // cluster means for labels 0..3 (mu_d); mu[0] == 0
#pragma unroll
        for (int e = 0; e < NE; ++e) mu[0][e] = 0.f;

        float Lvar = 0.f;
#pragma unroll
        for (int l = 1; l <= 4; ++l) {
            const float c   = a[l - 1];
            const float ssq = a[4 + (l - 1)];
            float mloc[NE];
            float musq = 0.f;
#pragma unroll
            for (int e = 0; e < NE; ++e) {
                mloc[e] = a[8 + (l - 1) * NE + e] / c;
                musq = fmaf(mloc[e], mloc[e], musq);
            }
            const float frob = ssq - c * musq;
            const float n = (frob > 0.f) ? sqrtf(frob) : 0.f;
            const float dv = n - 0.5f;               // DELTA_V = 0.5
            Lvar += (n > 0.5f) ? dv * dv : 0.f;
            if (l < 4) {
#pragma unroll
                for (int e = 0; e < NE; ++e) mu[l][e] = mloc[e];
            }
        }
        Lvar *= 0.25f;  // / C

        float Ldist = 0.f;
#pragma unroll
        for (int i = 0; i < 4; ++i)
#pragma unroll
            for (int j = i + 1; j < 4; ++j) {
                float dsq = 0.f;
#pragma unroll
                for (int e = 0; e < NE; ++e) {
                    const float d = mu[i][e] - mu[j][e];
                    dsq = fmaf(d, d, dsq);
                }
                float h;
                if (dsq > 0.f) {
                    const float d = sqrtf(dsq);
                    float r = 3.0f - d;              // DELTA_D = 3.0
                    r = (r > 0.f) ? r : 0.f;
                    h = r * r;
                } else {
                    h = 9.0f;                        // DELTA_D^2
                }
                Ldist += 2.0f * h;                   // both (i,j) and (j,i)
            }

        Lb = (Lvar + Ldist) * (1.0f / NB);           // mean over B of both terms
    }
    Lb += __shfl_down(Lb, 32);
    Lb += __shfl_down(Lb, 16);
    Lb += __shfl_down(Lb, 8);
    Lb += __shfl_down(Lb, 4);
    Lb += __shfl_down(Lb, 2);
    Lb += __shfl_down(Lb, 1);
    if (t == 0) out[0] = Lb;
}

extern "C" void kernel_launch(void* const* d_in, const int* in_sizes, int n_in,
                              void* d_out, int out_size, void* d_ws, size_t ws_size,
                              hipStream_t stream) {
    const float* pred = (const float*)d_in[0];
    // d_in[1] = binary_label: unused — it is exactly (instance_label > 0).
    const int* lab = (const int*)d_in[2];
    float* out = (float*)d_out;
    float* acc = (float*)d_ws;   // NB*40 floats = 2560 B, ws is poisoned -> zero it

    (void)hipMemsetAsync(acc, 0, NB * ACC_STRIDE * sizeof(float), stream);
    cluster_partial<<<NB * CHUNKS, TPB, 0, stream>>>(pred, lab, acc);
    cluster_finalize<<<1, 64, 0, stream>>>(acc, out);
}